// Round 4
// baseline (277.033 us; speedup 1.0000x reference)
//
#include <hip/hip_runtime.h>

#define NN 50000
#define NE 1250000
#define DD 64

// ---------------------------------------------------------------------------
// ws layout: cnt[50048] ints, then Wt[64*64] floats.
// d_out doubles as the per-node edge bucket (64 packed u32 payloads == one
// output row); agg consumes a node's bucket before overwriting that row.
// payload = src(16b) | (ef1*8+ef0)(5b)<<16.
// ---------------------------------------------------------------------------

// Scatter (4 edges/thread, int4 loads) + W-transpose piggybacked on the
// first 16 blocks. Degrees ~Poisson(25); pos<64 guard is belt-and-braces.
__global__ __launch_bounds__(256) void k_scatter(
    const int4* __restrict__ src4, const int4* __restrict__ dst4,
    const int4* __restrict__ ef04, const int4* __restrict__ ef14,
    const float* __restrict__ W, float* __restrict__ Wt,
    int* __restrict__ cnt, unsigned* __restrict__ bucket)
{
    const int t = blockIdx.x * 256 + threadIdx.x;
    if (t < 4096) Wt[(t & 63) * DD + (t >> 6)] = W[t];   // transpose W

    if (t * 4 >= NE) return;
    const int4 s  = src4[t];
    const int4 d  = dst4[t];
    const int4 f0 = ef04[t];
    const int4 f1 = ef14[t];

    int pos;
    pos = atomicAdd(&cnt[d.x], 1);
    if (pos < DD) bucket[(size_t)d.x * DD + pos] =
        (unsigned)s.x | ((unsigned)(f1.x * 8 + f0.x) << 16);
    pos = atomicAdd(&cnt[d.y], 1);
    if (pos < DD) bucket[(size_t)d.y * DD + pos] =
        (unsigned)s.y | ((unsigned)(f1.y * 8 + f0.y) << 16);
    pos = atomicAdd(&cnt[d.z], 1);
    if (pos < DD) bucket[(size_t)d.z * DD + pos] =
        (unsigned)s.z | ((unsigned)(f1.z * 8 + f0.z) << 16);
    pos = atomicAdd(&cnt[d.w], 1);
    if (pos < DD) bucket[(size_t)d.w * DD + pos] =
        (unsigned)s.w | ((unsigned)(f1.w * 8 + f0.w) << 16);
}

// ---------------------------------------------------------------------------
// Fused aggregation + MessageNorm + residual + GEMM. One wave per node,
// lane = feature dim. Bucket row loaded coalesced (1 dword/lane), payloads
// broadcast via v_readlane (SGPR -> scalar-base gathers), edge loop
// unrolled x8, next node's bucket prefetched.
// ---------------------------------------------------------------------------
__global__ __launch_bounds__(256, 4) void genconv_agg(
    const float* __restrict__ nf,
    const float* __restrict__ emb0, const float* __restrict__ emb1,
    const float* __restrict__ Wt,  const float* __restrict__ b,
    const float* __restrict__ beta_p, const float* __restrict__ scale_p,
    const int* __restrict__ cnt,
    float* out)
{
    __shared__ float emb_s[32 * DD];   // [f1*8+f0][lane]
    __shared__ float feat_s[4][DD];

    const int w    = threadIdx.x >> 6;
    const int lane = threadIdx.x & 63;

    for (int i = threadIdx.x; i < 32 * DD; i += 256) {
        const int r = i >> 6, c = i & 63;
        emb_s[i] = emb0[(r & 7) * DD + c] + emb1[(r >> 3) * DD + c];
    }

    float4 wc[16];   // this lane's W column (contiguous in Wt)
#pragma unroll
    for (int k = 0; k < 16; ++k)
        wc[k] = *(const float4*)(Wt + lane * DD + 4 * k);

    const float bias  = b[lane];
    const float beta  = beta_p[0];
    const float scale = scale_p[0];
    __syncthreads();

    const unsigned* bucket = (const unsigned*)out;
    const int stride = gridDim.x * 4;

    int node = blockIdx.x * 4 + w;                       // < 16384 < NN always
    unsigned pl = bucket[(size_t)node * DD + lane];
    int cn = min(cnt[node], DD);

    while (node < NN) {
        // prefetch next node's bucket row + degree (same wave owns it)
        const int nnext = node + stride;
        unsigned pl_n = 0u;
        int cn_n = 0;
        if (nnext < NN) {
            pl_n = bucket[(size_t)nnext * DD + lane];
            cn_n = cnt[nnext];
        }
        const float f = nf[(size_t)node * DD + lane];    // issue early

        float num = 0.0f, den = 0.0f;
        int j = 0;
        for (; j + 8 <= cn; j += 8) {
            float a[8], eb[8];
#pragma unroll
            for (int u = 0; u < 8; ++u) {
                const unsigned q =
                    (unsigned)__builtin_amdgcn_readlane((int)pl, j + u);
                a[u]  = nf[(size_t)(q & 0xFFFFu) * DD + lane];  // saddr gather
                eb[u] = emb_s[((q >> 16) << 6) + lane];
            }
#pragma unroll
            for (int u = 0; u < 8; ++u) {
                const float m = fmaxf(a[u] + eb[u], 0.0f) + 1e-7f;
                const float x = __expf(beta * m);
                den += x;
                num = fmaf(m, x, num);
            }
        }
        for (; j < cn; ++j) {
            const unsigned q = (unsigned)__builtin_amdgcn_readlane((int)pl, j);
            const float a  = nf[(size_t)(q & 0xFFFFu) * DD + lane];
            const float eb = emb_s[((q >> 16) << 6) + lane];
            const float m  = fmaxf(a + eb, 0.0f) + 1e-7f;
            const float x  = __expf(beta * m);
            den += x;
            num = fmaf(m, x, num);
        }

        const float msg = (den > 0.0f) ? num / den : 0.0f;

        float ss = msg * msg;
        float fs = f * f;
#pragma unroll
        for (int m = 32; m >= 1; m >>= 1) {
            ss += __shfl_xor(ss, m, 64);
            fs += __shfl_xor(fs, m, 64);
        }

        const float feat =
            f + msg * (1.0f / fmaxf(sqrtf(ss), 1e-12f)) * sqrtf(fs) * scale;

        feat_s[w][lane] = feat;   // wave-private row; same-wave DS ordering safe

        float acc = bias;
#pragma unroll
        for (int k = 0; k < 16; ++k) {
            const float4 fv = *(const float4*)&feat_s[w][4 * k];  // broadcast
            acc = fmaf(fv.x, wc[k].x, acc);
            acc = fmaf(fv.y, wc[k].y, acc);
            acc = fmaf(fv.z, wc[k].z, acc);
            acc = fmaf(fv.w, wc[k].w, acc);
        }
        out[(size_t)node * DD + lane] = acc;   // overwrites consumed bucket row

        node = nnext;
        pl = pl_n;
        cn = min(cn_n, DD);
    }
}

extern "C" void kernel_launch(void* const* d_in, const int* in_sizes, int n_in,
                              void* d_out, int out_size, void* d_ws, size_t ws_size,
                              hipStream_t stream)
{
    const float* nf    = (const float*)d_in[0];
    const float* emb0  = (const float*)d_in[1];
    const float* emb1  = (const float*)d_in[2];
    const float* W     = (const float*)d_in[3];
    const float* b     = (const float*)d_in[4];
    const float* beta  = (const float*)d_in[5];
    const float* scale = (const float*)d_in[6];
    const int* src = (const int*)d_in[7];
    const int* dst = (const int*)d_in[8];
    const int* ef0 = (const int*)d_in[9];
    const int* ef1 = (const int*)d_in[10];

    int*   cnt = (int*)d_ws;            // 50048 ints
    float* Wt  = (float*)(cnt + 50048); // 4096 floats

    hipMemsetAsync(cnt, 0, 50048 * sizeof(int), stream);

    k_scatter<<<(NE / 4 + 255) / 256, 256, 0, stream>>>(
        (const int4*)src, (const int4*)dst, (const int4*)ef0, (const int4*)ef1,
        W, Wt, cnt, (unsigned*)d_out);

    genconv_agg<<<4096, 256, 0, stream>>>(
        nf, emb0, emb1, Wt, b, beta, scale, cnt, (float*)d_out);
}

// Round 5
// 267.185 us; speedup vs baseline: 1.0369x; 1.0369x over previous
//
#include <hip/hip_runtime.h>

#define NN 50000
#define NE 1250000
#define DD 64
#define CSH 4          // cnt stride shift: one counter per 64B line (16 ints)

// ---------------------------------------------------------------------------
// ws layout: cnt[50000<<CSH] ints (padded: 1 counter / 64B line, kills
// same-line atomic contention), then Wt[64*64] floats.
// d_out doubles as the per-node edge bucket (64 packed u32 payloads == one
// output row); agg consumes a node's bucket before overwriting that row.
// payload = src(16b) | (ef1*8+ef0)(5b)<<16.
// ---------------------------------------------------------------------------

// Scatter (4 edges/thread, int4 loads) + W-transpose piggybacked.
__global__ __launch_bounds__(256) void k_scatter(
    const int4* __restrict__ src4, const int4* __restrict__ dst4,
    const int4* __restrict__ ef04, const int4* __restrict__ ef14,
    const float* __restrict__ W, float* __restrict__ Wt,
    int* __restrict__ cnt, unsigned* __restrict__ bucket)
{
    const int t = blockIdx.x * 256 + threadIdx.x;
    if (t < 4096) Wt[(t & 63) * DD + (t >> 6)] = W[t];   // transpose W

    if (t * 4 >= NE) return;
    const int4 s  = src4[t];
    const int4 d  = dst4[t];
    const int4 f0 = ef04[t];
    const int4 f1 = ef14[t];

    const int p0 = atomicAdd(&cnt[d.x << CSH], 1);
    const int p1 = atomicAdd(&cnt[d.y << CSH], 1);
    const int p2 = atomicAdd(&cnt[d.z << CSH], 1);
    const int p3 = atomicAdd(&cnt[d.w << CSH], 1);
    if (p0 < DD) bucket[(size_t)d.x * DD + p0] =
        (unsigned)s.x | ((unsigned)(f1.x * 8 + f0.x) << 16);
    if (p1 < DD) bucket[(size_t)d.y * DD + p1] =
        (unsigned)s.y | ((unsigned)(f1.y * 8 + f0.y) << 16);
    if (p2 < DD) bucket[(size_t)d.z * DD + p2] =
        (unsigned)s.z | ((unsigned)(f1.z * 8 + f0.z) << 16);
    if (p3 < DD) bucket[(size_t)d.w * DD + p3] =
        (unsigned)s.w | ((unsigned)(f1.w * 8 + f0.w) << 16);
}

// ---------------------------------------------------------------------------
// Fused aggregation + MessageNorm + residual + GEMM. One wave per node,
// lane = feature dim. Bucket row loaded coalesced (1 dword/lane), payloads
// broadcast via v_readlane (SGPR -> scalar-base gathers). Edge loop in
// batches of 16 with predicated tail (no serial remainder): 16 gathers in
// flight. Masked slots clamp src to a valid row and zero x, so num/den are
// untouched and all arithmetic stays finite.
// ---------------------------------------------------------------------------
__global__ __launch_bounds__(256, 4) void genconv_agg(
    const float* __restrict__ nf,
    const float* __restrict__ emb0, const float* __restrict__ emb1,
    const float* __restrict__ Wt,  const float* __restrict__ b,
    const float* __restrict__ beta_p, const float* __restrict__ scale_p,
    const int* __restrict__ cnt,
    float* out)
{
    __shared__ float emb_s[32 * DD];   // [f1*8+f0][lane]
    __shared__ float feat_s[4][DD];

    const int w    = threadIdx.x >> 6;
    const int lane = threadIdx.x & 63;

    for (int i = threadIdx.x; i < 32 * DD; i += 256) {
        const int r = i >> 6, c = i & 63;
        emb_s[i] = emb0[(r & 7) * DD + c] + emb1[(r >> 3) * DD + c];
    }

    float4 wc[16];   // this lane's W column (contiguous in Wt)
#pragma unroll
    for (int k = 0; k < 16; ++k)
        wc[k] = *(const float4*)(Wt + lane * DD + 4 * k);

    const float bias  = b[lane];
    const float beta  = beta_p[0];
    const float scale = scale_p[0];
    __syncthreads();

    const unsigned* bucket = (const unsigned*)out;
    const int stride = gridDim.x * 4;

    int node = blockIdx.x * 4 + w;                       // < 16384 < NN always
    unsigned pl = bucket[(size_t)node * DD + lane];
    int cn = min(cnt[node << CSH], DD);

    while (node < NN) {
        // prefetch next node's bucket row + degree (same wave owns it)
        const int nnext = node + stride;
        unsigned pl_n = 0u;
        int cn_n = 0;
        if (nnext < NN) {
            pl_n = bucket[(size_t)nnext * DD + lane];
            cn_n = cnt[nnext << CSH];
        }
        const float f = nf[(size_t)node * DD + lane];    // issue early

        float num = 0.0f, den = 0.0f;
        for (int j = 0; j < cn; j += 16) {
            float a[16];
            unsigned qv[16];
#pragma unroll
            for (int u = 0; u < 16; ++u) {
                const unsigned q =
                    (unsigned)__builtin_amdgcn_readlane((int)pl, (j + u) & 63);
                qv[u] = q;
                const int s = min((int)(q & 0xFFFFu), NN - 1);  // clamp garbage
                a[u] = nf[(size_t)s * DD + lane];               // saddr gather
            }
#pragma unroll
            for (int u = 0; u < 16; ++u) {
                const float eb = emb_s[(((qv[u] >> 16) & 31) << 6) + lane];
                const float m  = fmaxf(a[u] + eb, 0.0f) + 1e-7f;
                float x = __expf(beta * m);
                x = (j + u < cn) ? x : 0.0f;   // mask tail slots
                den += x;
                num = fmaf(m, x, num);
            }
        }

        const float msg = (den > 0.0f) ? num / den : 0.0f;

        float ss = msg * msg;
        float fs = f * f;
#pragma unroll
        for (int m = 32; m >= 1; m >>= 1) {
            ss += __shfl_xor(ss, m, 64);
            fs += __shfl_xor(fs, m, 64);
        }

        const float feat =
            f + msg * (1.0f / fmaxf(sqrtf(ss), 1e-12f)) * sqrtf(fs) * scale;

        feat_s[w][lane] = feat;   // wave-private row; same-wave DS ordering safe

        float acc = bias;
#pragma unroll
        for (int k = 0; k < 16; ++k) {
            const float4 fv = *(const float4*)&feat_s[w][4 * k];  // broadcast
            acc = fmaf(fv.x, wc[k].x, acc);
            acc = fmaf(fv.y, wc[k].y, acc);
            acc = fmaf(fv.z, wc[k].z, acc);
            acc = fmaf(fv.w, wc[k].w, acc);
        }
        out[(size_t)node * DD + lane] = acc;   // overwrites consumed bucket row

        node = nnext;
        pl = pl_n;
        cn = min(cn_n, DD);
    }
}

extern "C" void kernel_launch(void* const* d_in, const int* in_sizes, int n_in,
                              void* d_out, int out_size, void* d_ws, size_t ws_size,
                              hipStream_t stream)
{
    const float* nf    = (const float*)d_in[0];
    const float* emb0  = (const float*)d_in[1];
    const float* emb1  = (const float*)d_in[2];
    const float* W     = (const float*)d_in[3];
    const float* b     = (const float*)d_in[4];
    const float* beta  = (const float*)d_in[5];
    const float* scale = (const float*)d_in[6];
    const int* src = (const int*)d_in[7];
    const int* dst = (const int*)d_in[8];
    const int* ef0 = (const int*)d_in[9];
    const int* ef1 = (const int*)d_in[10];

    int*   cnt = (int*)d_ws;                      // 50000<<CSH ints (3.2 MB)
    float* Wt  = (float*)(cnt + (NN << CSH) + 64);

    hipMemsetAsync(cnt, 0, ((size_t)NN << CSH) * sizeof(int), stream);

    k_scatter<<<(NE / 4 + 255) / 256, 256, 0, stream>>>(
        (const int4*)src, (const int4*)dst, (const int4*)ef0, (const int4*)ef1,
        W, Wt, cnt, (unsigned*)d_out);

    genconv_agg<<<4096, 256, 0, stream>>>(
        nf, emb0, emb1, Wt, b, beta, scale, cnt, (float*)d_out);
}

// Round 6
// 197.813 us; speedup vs baseline: 1.4005x; 1.3507x over previous
//
#include <hip/hip_runtime.h>

#define NN 50000
#define NE 1250000
#define DD 64
#define KR 391        // node ranges of 128 (50000/128 -> 391)
#define RSH 7         // nodes per range = 128
#define RCAP 4096     // staged-edge capacity per range (avg 3200, +15 sigma)
#define RCSH 12       // log2(RCAP)

// ---------------------------------------------------------------------------
// ws layout: rcur[512] | cnt[50048] | Wt[4096] f32 | staging[KR*RCAP] u32
// d_out doubles as the per-node edge bucket (64 packed u32 == one output
// row); agg consumes a node's bucket before overwriting that row.
// staging payload = src(16b) | (ef1*8+ef0)(5b)<<16 | (dst&127)(7b)<<21
// bucket payload  = low 21 bits of the above.
// ---------------------------------------------------------------------------

// Phase A: range-partition edges. LDS histogram -> one global atomicAdd per
// (block,bin) -> append ~10-edge contiguous runs per bin (dense-ish writes,
// kills the 64B-line write amplification that bound R5's scatter).
__global__ __launch_bounds__(512) void k_part(
    const int4* __restrict__ src4, const int4* __restrict__ dst4,
    const int4* __restrict__ ef04, const int4* __restrict__ ef14,
    const float* __restrict__ W, float* __restrict__ Wt,
    int* __restrict__ rcur, unsigned* __restrict__ staging)
{
    __shared__ int hist[KR], rbase[KR], cur[KR];
    const int t  = threadIdx.x;
    const int gb = blockIdx.x;

    for (int i = t; i < KR; i += 512) { hist[i] = 0; cur[i] = 0; }
    if (gb == 0)   // piggyback W transpose
        for (int i = t; i < 4096; i += 512)
            Wt[(i & 63) * DD + (i >> 6)] = W[i];
    __syncthreads();

    unsigned pay[8];
    int rr[8];
#pragma unroll
    for (int u = 0; u < 8; ++u) rr[u] = -1;

#pragma unroll
    for (int g = 0; g < 2; ++g) {
        const int i4 = gb * 1024 + t + g * 512;
        if (i4 < NE / 4) {
            const int4 s  = src4[i4], d = dst4[i4];
            const int4 f0 = ef04[i4], f1 = ef14[i4];
            const int ds[4] = {d.x, d.y, d.z, d.w};
            const int ss[4] = {s.x, s.y, s.z, s.w};
            const int a0[4] = {f0.x, f0.y, f0.z, f0.w};
            const int a1[4] = {f1.x, f1.y, f1.z, f1.w};
#pragma unroll
            for (int u = 0; u < 4; ++u) {
                const int k = g * 4 + u;
                rr[k]  = ds[u] >> RSH;
                pay[k] = (unsigned)ss[u] | ((unsigned)(a1[u] * 8 + a0[u]) << 16)
                         | ((unsigned)(ds[u] & 127) << 21);
            }
        }
    }
#pragma unroll
    for (int u = 0; u < 8; ++u)
        if (rr[u] >= 0) atomicAdd(&hist[rr[u]], 1);
    __syncthreads();

    for (int i = t; i < KR; i += 512) {
        const int h = hist[i];
        if (h) rbase[i] = atomicAdd(&rcur[i], h);
    }
    __syncthreads();

#pragma unroll
    for (int u = 0; u < 8; ++u) {
        if (rr[u] >= 0) {
            const int r   = rr[u];
            const int pos = rbase[r] + atomicAdd(&cur[r], 1);
            if (pos < RCAP) staging[(r << RCSH) + pos] = pay[u];
        }
    }
}

// Phase B: one block per range. Build 128-node bucket in LDS (LDS atomics,
// free), then stream full-line coalesced writes to d_out + dense cnt.
__global__ __launch_bounds__(256) void k_bucket(
    const unsigned* __restrict__ staging, const int* __restrict__ rcur,
    int* __restrict__ cnt, unsigned* __restrict__ bucket)
{
    __shared__ unsigned buck[128 * DD];   // 32 KB
    __shared__ int ldeg[128];
    const int t = threadIdx.x;
    const int r = blockIdx.x;

    if (t < 128) ldeg[t] = 0;
    __syncthreads();

    const int ne = min(rcur[r], RCAP);
    for (int i = t; i < ne; i += 256) {
        const unsigned p = staging[(r << RCSH) + i];
        const int d = (p >> 21) & 127;
        const int pos = atomicAdd(&ldeg[d], 1);
        if (pos < DD) buck[(d << 6) + pos] = p & 0x1FFFFFu;
    }
    __syncthreads();

    const int base_node = r << RSH;
    const int nnodes = min(128, NN - base_node);
    for (int i = t; i < nnodes * DD; i += 256)
        bucket[((size_t)base_node << 6) + i] = buck[i];
    if (t < nnodes) cnt[base_node + t] = min(ldeg[t], DD);
}

// ---------------------------------------------------------------------------
// Fused aggregation + MessageNorm + residual + GEMM (unchanged from R5
// except dense cnt). One wave per node, lane = feature dim.
// ---------------------------------------------------------------------------
__global__ __launch_bounds__(256, 4) void genconv_agg(
    const float* __restrict__ nf,
    const float* __restrict__ emb0, const float* __restrict__ emb1,
    const float* __restrict__ Wt,  const float* __restrict__ b,
    const float* __restrict__ beta_p, const float* __restrict__ scale_p,
    const int* __restrict__ cnt,
    float* out)
{
    __shared__ float emb_s[32 * DD];
    __shared__ float feat_s[4][DD];

    const int w    = threadIdx.x >> 6;
    const int lane = threadIdx.x & 63;

    for (int i = threadIdx.x; i < 32 * DD; i += 256) {
        const int r = i >> 6, c = i & 63;
        emb_s[i] = emb0[(r & 7) * DD + c] + emb1[(r >> 3) * DD + c];
    }

    float4 wc[16];
#pragma unroll
    for (int k = 0; k < 16; ++k)
        wc[k] = *(const float4*)(Wt + lane * DD + 4 * k);

    const float bias  = b[lane];
    const float beta  = beta_p[0];
    const float scale = scale_p[0];
    __syncthreads();

    const unsigned* bucket = (const unsigned*)out;
    const int stride = gridDim.x * 4;

    int node = blockIdx.x * 4 + w;
    unsigned pl = bucket[(size_t)node * DD + lane];
    int cn = min(cnt[node], DD);

    while (node < NN) {
        const int nnext = node + stride;
        unsigned pl_n = 0u;
        int cn_n = 0;
        if (nnext < NN) {
            pl_n = bucket[(size_t)nnext * DD + lane];
            cn_n = cnt[nnext];
        }
        const float f = nf[(size_t)node * DD + lane];

        float num = 0.0f, den = 0.0f;
        for (int j = 0; j < cn; j += 16) {
            float a[16];
            unsigned qv[16];
#pragma unroll
            for (int u = 0; u < 16; ++u) {
                const unsigned q =
                    (unsigned)__builtin_amdgcn_readlane((int)pl, (j + u) & 63);
                qv[u] = q;
                const int s = min((int)(q & 0xFFFFu), NN - 1);  // clamp garbage
                a[u] = nf[(size_t)s * DD + lane];
            }
#pragma unroll
            for (int u = 0; u < 16; ++u) {
                const float eb = emb_s[(((qv[u] >> 16) & 31) << 6) + lane];
                const float m  = fmaxf(a[u] + eb, 0.0f) + 1e-7f;
                float x = __expf(beta * m);
                x = (j + u < cn) ? x : 0.0f;   // mask tail slots
                den += x;
                num = fmaf(m, x, num);
            }
        }

        const float msg = (den > 0.0f) ? num / den : 0.0f;

        float ss = msg * msg;
        float fs = f * f;
#pragma unroll
        for (int m = 32; m >= 1; m >>= 1) {
            ss += __shfl_xor(ss, m, 64);
            fs += __shfl_xor(fs, m, 64);
        }

        const float feat =
            f + msg * (1.0f / fmaxf(sqrtf(ss), 1e-12f)) * sqrtf(fs) * scale;

        feat_s[w][lane] = feat;

        float acc = bias;
#pragma unroll
        for (int k = 0; k < 16; ++k) {
            const float4 fv = *(const float4*)&feat_s[w][4 * k];
            acc = fmaf(fv.x, wc[k].x, acc);
            acc = fmaf(fv.y, wc[k].y, acc);
            acc = fmaf(fv.z, wc[k].z, acc);
            acc = fmaf(fv.w, wc[k].w, acc);
        }
        out[(size_t)node * DD + lane] = acc;

        node = nnext;
        pl = pl_n;
        cn = min(cn_n, DD);
    }
}

extern "C" void kernel_launch(void* const* d_in, const int* in_sizes, int n_in,
                              void* d_out, int out_size, void* d_ws, size_t ws_size,
                              hipStream_t stream)
{
    const float* nf    = (const float*)d_in[0];
    const float* emb0  = (const float*)d_in[1];
    const float* emb1  = (const float*)d_in[2];
    const float* W     = (const float*)d_in[3];
    const float* b     = (const float*)d_in[4];
    const float* beta  = (const float*)d_in[5];
    const float* scale = (const float*)d_in[6];
    const int* src = (const int*)d_in[7];
    const int* dst = (const int*)d_in[8];
    const int* ef0 = (const int*)d_in[9];
    const int* ef1 = (const int*)d_in[10];

    int*      rcur    = (int*)d_ws;                 // 512
    int*      cnt     = rcur + 512;                 // 50048
    float*    Wt      = (float*)(cnt + 50048);      // 4096
    unsigned* staging = (unsigned*)(Wt + 4096);     // KR*RCAP (~6.1 MB)

    hipMemsetAsync(rcur, 0, 512 * sizeof(int), stream);

    k_part<<<(NE / 4 + 1023) / 1024, 512, 0, stream>>>(
        (const int4*)src, (const int4*)dst, (const int4*)ef0, (const int4*)ef1,
        W, Wt, rcur, staging);

    k_bucket<<<KR, 256, 0, stream>>>(staging, rcur, cnt, (unsigned*)d_out);

    genconv_agg<<<4096, 256, 0, stream>>>(
        nf, emb0, emb1, Wt, b, beta, scale, cnt, (float*)d_out);
}